// Round 10
// baseline (213.660 us; speedup 1.0000x reference)
//
#include <hip/hip_runtime.h>
#include <hip/hip_bf16.h>
#include <math.h>

// B=2 S=2048 E=1024 H=16 HD=64
#define BB 2
#define SS 2048
#define EE 1024
#define HH 16
#define HD 64
#define NBLK 512

typedef __bf16 bf16;
typedef __bf16 bf16x8 __attribute__((ext_vector_type(8)));
typedef float floatx4 __attribute__((ext_vector_type(4)));
typedef float floatx16 __attribute__((ext_vector_type(16)));

#define MFMA(a, b, c) __builtin_amdgcn_mfma_f32_16x16x32_bf16(a, b, c, 0, 0, 0)
#define MFMA32(a, b, c) __builtin_amdgcn_mfma_f32_32x32x16_bf16(a, b, c, 0, 0, 0)

// async global->LDS, 16 bytes/lane (global_load_lds_dwordx4)
__device__ inline void async16(const bf16* g, bf16* l) {
    __builtin_amdgcn_global_load_lds(
        (const __attribute__((address_space(1))) void*)g,
        (__attribute__((address_space(3))) void*)l, 16, 0, 0);
}

__device__ inline unsigned cvt_pk_bf16(float a, float b) {
    unsigned r;
    asm("v_cvt_pk_bf16_f32 %0, %1, %2" : "=v"(r) : "v"(a), "v"(b));
    return r;
}

__device__ inline float fast_exp2(float x) {
    float r;
    asm("v_exp_f32 %0, %1" : "=v"(r) : "v"(x));
    return r;
}

// ---------------- Kernel 0: fp32 -> bf16 convert (query, qkv_w, out_w) ------
__global__ __launch_bounds__(256) void cvt3(
    const float* __restrict__ a, const float* __restrict__ b,
    const float* __restrict__ c,
    bf16* __restrict__ oa, bf16* __restrict__ ob, bf16* __restrict__ oc) {
    const long NA = (long)4096 * 1024, NB = (long)3072 * 1024, NC = (long)1024 * 1024;
    const long total = (NA + NB + NC) >> 2;
    long i = (long)blockIdx.x * blockDim.x + threadIdx.x;
    const long stride = (long)gridDim.x * blockDim.x;
    for (; i < total; i += stride) {
        const long e = i << 2;
        const float* src;
        bf16* dst;
        if (e < NA)           { src = a + e;            dst = oa + e; }
        else if (e < NA + NB) { src = b + (e - NA);     dst = ob + (e - NA); }
        else                  { src = c + (e - NA - NB); dst = oc + (e - NA - NB); }
        float4 v = *(const float4*)src;
        union { bf16 h[4]; uint2 u; } t;
        t.h[0] = (bf16)v.x; t.h[1] = (bf16)v.y; t.h[2] = (bf16)v.z; t.h[3] = (bf16)v.w;
        *(uint2*)dst = t.u;
    }
}

// ---------------- Kernel 1: QKV projection, 8-wave K-SPLIT 128x128x64 ------
// Round-10: LDS-pipe reduction. The r8 8-wave version issued 96 ds_read_b128
// per K-step (12/wave: af[4]+bfr[2] x 2 c-chunks) for 128 MFMAs -> ~1.18 GB
// LDS fragment reads (~17us at the 69 TB/s ceiling) + staging ~6us: LDS was
// the dominant pipe (~23 of ~38us; MFMA floor 10.3). K-SPLIT: waves 0-3
// compute only c=0, waves 4-7 only c=1; wave-tile grows to 64x64 (acc[4][4]);
// reads/wave/step 12 -> 8 for the same 16 MFMAs (block 96 -> 64, -33%).
// The two K-halves are summed per tile via a conflict-free 64 KB LDS
// exchange (contiguous 16B/lane slots); grp0 adds + runs the round-5
// verified 64x64 epilogue verbatim. Staging/swizzle/dbuf unchanged from r8.
__global__ __launch_bounds__(512, 4) void qkv_gemm(
    const bf16* __restrict__ A, const bf16* __restrict__ W,
    const float* __restrict__ bias,
    bf16* __restrict__ Qw, bf16* __restrict__ Kw, bf16* __restrict__ Vtw) {
    __shared__ __align__(16) bf16 smem[32768];   // 64 KB: As0|As1|Bs0|Bs1
    const int bid  = blockIdx.x;
    const int tid  = threadIdx.x;
    const int wave = tid >> 6, lane = tid & 63;
    const int quad = lane >> 4, l16 = lane & 15;
    const int grp = wave >> 2, w4 = wave & 3;        // grp = k-chunk owner
    const int wr = w4 >> 1, wc = w4 & 1;             // wave-tile 64m x 64n
    const int lr = lane >> 3;
    const int lcs = ((lane & 7) ^ (lr & 7)) * 8;     // swizzled source col
    const int rsw = (l16 & 7) << 3;                  // read-side XOR (elems)
    bf16* As0 = smem;         bf16* As1 = smem + 8192;
    bf16* Bs0 = smem + 16384; bf16* Bs1 = smem + 24576;
    const bool stA = wave < 4;                       // waves 0-3 stage A, 4-7 B
    bf16* L0g = (stA ? As0 : Bs0) + w4 * 2048 + lane * 8;
    bf16* L1g = (stA ? As1 : Bs1) + w4 * 2048 + lane * 8;
    const int ccol = grp * 32 + quad * 8;            // this wave's k-chunk cols

    for (int tile = bid; tile < 768; tile += NBLK) {
        const int m0 = (tile / 24) * 128, n0 = (tile % 24) * 128;
        const bf16* G = stA
            ? (A + (long)(m0 + w4 * 32 + lr) * 1024 + lcs)
            : (W + (long)(n0 + w4 * 32 + lr) * 1024 + lcs);
        floatx4 acc[4][4] = {};
#pragma unroll
        for (int j = 0; j < 4; ++j)
            async16(G + (long)j * 8 * 1024, L0g + j * 512);
        for (int ks = 0; ks < 16; ++ks) {
            __syncthreads();   // drains vmcnt: buf cur ready; readers of nxt done
            if (ks < 15) {
                bf16* Ln = (ks & 1) ? L0g : L1g;
                const int k0 = (ks + 1) * 64;
#pragma unroll
                for (int j = 0; j < 4; ++j)
                    async16(G + (long)j * 8 * 1024 + k0, Ln + j * 512);
            }
            const bf16* Ac = (ks & 1) ? As1 : As0;
            const bf16* Bc = (ks & 1) ? Bs1 : Bs0;
            bf16x8 af[4], bfr[4];
#pragma unroll
            for (int mi = 0; mi < 4; ++mi)
                af[mi] = *(const bf16x8*)&Ac[(wr * 64 + mi * 16 + l16) * 64 + (ccol ^ rsw)];
#pragma unroll
            for (int ni = 0; ni < 4; ++ni)
                bfr[ni] = *(const bf16x8*)&Bc[(wc * 64 + ni * 16 + l16) * 64 + (ccol ^ rsw)];
#pragma unroll
            for (int mi = 0; mi < 4; ++mi)
#pragma unroll
                for (int ni = 0; ni < 4; ++ni)
                    acc[mi][ni] = MFMA(af[mi], bfr[ni], acc[mi][ni]);
        }

        // ---- combine K-halves: grp1 -> LDS (conflict-free), grp0 adds ----
        __syncthreads();                   // all tile LDS reads done; reusable
        float* xb = (float*)smem;          // [16 slot][4 w4][64 lane] x 16B
        if (grp == 1) {
#pragma unroll
            for (int mi = 0; mi < 4; ++mi)
#pragma unroll
                for (int ni = 0; ni < 4; ++ni)
                    *(floatx4*)&xb[(((mi * 4 + ni) * 4 + w4) * 64 + lane) * 4] = acc[mi][ni];
        }
        __syncthreads();
        if (grp == 0) {
#pragma unroll
            for (int mi = 0; mi < 4; ++mi)
#pragma unroll
                for (int ni = 0; ni < 4; ++ni) {
                    acc[mi][ni] += *(const floatx4*)&xb[(((mi * 4 + ni) * 4 + w4) * 64 + lane) * 4];
                    const int n = n0 + wc * 64 + ni * 16 + l16;
                    const float bn = bias[n];
                    const int sel = n >> 10;       // 0:Q 1:K 2:V (uniform/block)
                    const int e = n & 1023, h = e >> 6, d = e & 63;
                    if (sel == 2) {
                        const int m_base = m0 + wr * 64 + mi * 16 + quad * 4;
                        const int b = m_base >> 11, s0 = m_base & 2047;
                        union { bf16 h4[4]; uint2 u; } t;
#pragma unroll
                        for (int r = 0; r < 4; ++r)
                            t.h4[r] = (bf16)(acc[mi][ni][r] + bn);
                        *(uint2*)&Vtw[((long)(b * HH + h) * HD + d) * SS + s0] = t.u;
                    } else {
#pragma unroll
                        for (int r = 0; r < 4; ++r) {
                            const int m = m0 + wr * 64 + mi * 16 + quad * 4 + r;
                            const int b = m >> 11, s = m & 2047;
                            const float v = acc[mi][ni][r] + bn;
                            if (sel == 0)   // 1/sqrt(HD) * log2(e) for exp2
                                Qw[((long)(b * HH + h) * SS + s) * HD + d] = (bf16)(v * 0.18033688f);
                            else
                                Kw[((long)(b * HH + h) * SS + s) * HD + d] = (bf16)v;
                        }
                    }
                }
        }
        __syncthreads();   // combine reads + epilogue done before restage
    }
}

// ---------------- Kernel 2: attention, 8 waves, in-block 2-way KV split ----
// (round-5/8 passing version, unchanged)
__global__ __launch_bounds__(512) void attn(
    const bf16* __restrict__ Qw, const bf16* __restrict__ Kw,
    const bf16* __restrict__ Vtw, bf16* __restrict__ ctxw) {
    extern __shared__ __align__(16) bf16 smem[];

    const int tid = threadIdx.x;
    const int wave = tid >> 6, lane = tid & 63;
    const int grp = wave >> 2, w4 = wave & 3;
    const int l5 = lane & 31, hi = lane >> 5;

    // T1 remap: xcd = d&7 serves bh in [xcd*4, xcd*4+4) for all 16 qb.
    const int d_  = blockIdx.y * gridDim.x + blockIdx.x;
    const int j_  = d_ >> 3;
    const int bh  = (d_ & 7) * 4 + (j_ >> 4);
    const int qb  = j_ & 15;

    const bf16* Qh = Qw  + (long)bh * SS * HD;
    const bf16* Kh = Kw  + (long)bh * SS * HD;
    const bf16* Vh = Vtw + (long)bh * HD * SS;

    const int qbase = qb * 128 + w4 * 32;
    bf16x8 qf[4];
#pragma unroll
    for (int d0 = 0; d0 < 4; ++d0)
        qf[d0] = *(const bf16x8*)&Qh[(long)(qbase + l5) * HD + d0 * 16 + hi * 8];

    floatx16 ctx0 = {}, ctx1 = {};       // partial ctx over this group's KV half
    float lsum = 0.f;                    // partial row-sum for q = l5

    const int wrow = w4 * 8 + (lane >> 3);
    const int sch  = ((lane & 7) ^ ((lane >> 3) & 7)) * 8;
    const int kvo  = grp * 1024;          // this group's KV half
    const bf16* Kg0 = Kh + (long)(kvo + wrow) * HD + sch;
    const bf16* Kg1 = Kh + (long)(kvo + 32 + wrow) * HD + sch;
    const bf16* Vg0 = Vh + (long)wrow * SS + kvo + sch;
    const bf16* Vg1 = Vh + (long)(32 + wrow) * SS + kvo + sch;
    const int ldst = w4 * 512 + lane * 8;
    const int rswz = (l5 & 7) << 3;

    bf16* Kt0 = smem + (grp * 2 + 0) * 4096;
    bf16* Kt1 = smem + (grp * 2 + 1) * 4096;
    bf16* Vt0 = smem + 16384 + (grp * 2 + 0) * 4096;
    bf16* Vt1 = smem + 16384 + (grp * 2 + 1) * 4096;

    async16(Kg0, Kt0 + ldst);
    async16(Kg1, Kt0 + ldst + 2048);
    async16(Vg0, Vt0 + ldst);
    async16(Vg1, Vt0 + ldst + 2048);

    for (int kt = 0; kt < 16; ++kt) {
        __syncthreads();
        if (kt < 15) {
            bf16* Kn = (kt & 1) ? Kt0 : Kt1;
            bf16* Vn = (kt & 1) ? Vt0 : Vt1;
            const long ko = (long)(kt + 1) * 64;
            async16(Kg0 + ko * HD, Kn + ldst);
            async16(Kg1 + ko * HD, Kn + ldst + 2048);
            async16(Vg0 + ko,      Vn + ldst);
            async16(Vg1 + ko,      Vn + ldst + 2048);
        }
        const bf16* Kc = (kt & 1) ? Kt1 : Kt0;
        const bf16* Vc = (kt & 1) ? Vt1 : Vt0;

        floatx16 sf[2];
#pragma unroll
        for (int kb = 0; kb < 2; ++kb) {
            floatx16 s = {};
            __builtin_amdgcn_s_setprio(1);
#pragma unroll
            for (int d0 = 0; d0 < 4; ++d0) {
                const bf16x8 af = *(const bf16x8*)
                    &Kc[(kb * 32 + l5) * 64 + ((d0 * 16 + hi * 8) ^ rswz)];
                s = MFMA32(af, qf[d0], s);
            }
            __builtin_amdgcn_s_setprio(0);
            sf[kb] = s;
        }

#pragma unroll
        for (int kb = 0; kb < 2; ++kb) {
#pragma unroll
            for (int r = 0; r < 16; ++r) {
                const float p = fast_exp2(sf[kb][r]);
                sf[kb][r] = p;
                lsum += p;
            }
            unsigned w[8];
#pragma unroll
            for (int i = 0; i < 8; ++i)
                w[i] = cvt_pk_bf16(sf[kb][2 * i], sf[kb][2 * i + 1]);
            asm("v_permlane32_swap_b32 %0, %1" : "+v"(w[0]), "+v"(w[2]));
            asm("v_permlane32_swap_b32 %0, %1" : "+v"(w[1]), "+v"(w[3]));
            asm("v_permlane32_swap_b32 %0, %1" : "+v"(w[4]), "+v"(w[6]));
            asm("v_permlane32_swap_b32 %0, %1" : "+v"(w[5]), "+v"(w[7]));
            union { unsigned u[4]; bf16x8 v; } pa0 = {{w[0], w[1], w[2], w[3]}},
                                               pa1 = {{w[4], w[5], w[6], w[7]}};
#pragma unroll
            for (int kc = 0; kc < 2; ++kc) {
                const bf16x8 pa = kc ? pa1.v : pa0.v;
                const int kcol = kb * 32 + kc * 16 + hi * 8;
                const bf16x8 vf0 = *(const bf16x8*)&Vc[l5 * 64 + (kcol ^ rswz)];
                const bf16x8 vf1 = *(const bf16x8*)&Vc[(32 + l5) * 64 + (kcol ^ rswz)];
                __builtin_amdgcn_s_setprio(1);
                ctx0 = MFMA32(pa, vf0, ctx0);
                ctx1 = MFMA32(pa, vf1, ctx1);
                __builtin_amdgcn_s_setprio(0);
            }
        }
    }

    // combine the two KV halves (exact: no-rescale partials just add)
    __syncthreads();
    float* cb = (float*)smem;              // [4][32][64] = 32 KB
    float* lb = (float*)(smem + 16384);    // [4][64]
    if (grp == 1) {
#pragma unroll
        for (int r = 0; r < 16; ++r) {
            cb[(w4 * 32 + r) * 64 + lane]      = ctx0[r];
            cb[(w4 * 32 + 16 + r) * 64 + lane] = ctx1[r];
        }
        lb[w4 * 64 + lane] = lsum;
    }
    __syncthreads();
    if (grp == 0) {
        lsum += lb[w4 * 64 + lane];
#pragma unroll
        for (int r = 0; r < 16; ++r) {
            ctx0[r] += cb[(w4 * 32 + r) * 64 + lane];
            ctx1[r] += cb[(w4 * 32 + 16 + r) * 64 + lane];
        }
        const float rs  = lsum + __shfl_xor(lsum, 32, 64);
        const float inv = 1.0f / rs;

        const int b = bh >> 4, h = bh & 15;
#pragma unroll
        for (int r = 0; r < 16; ++r) {
            const int qrow = (r & 3) + 8 * (r >> 2) + 4 * hi;
            const float iq = __shfl(inv, qrow, 64);
            const long base = ((long)b * SS + qbase + qrow) * EE + h * HD;
            ctxw[base + l5]      = (bf16)(ctx0[r] * iq);
            ctxw[base + 32 + l5] = (bf16)(ctx1[r] * iq);
        }
    }
}

// ---------------- Kernel 3: output projection (64x128, 2-phase dbuf) -------
// (round-5/8 passing version, unchanged)
__global__ __launch_bounds__(256) void out_gemm(
    const bf16* __restrict__ A, const bf16* __restrict__ W,
    const float* __restrict__ bias, float* __restrict__ out) {
    __shared__ __align__(16) bf16 As[2][64 * 64];    // 2 x 8 KB
    __shared__ __align__(16) bf16 Bs[2][128 * 64];   // 2 x 16 KB
    const int tid  = threadIdx.x;
    const int wave = tid >> 6, lane = tid & 63;
    const int quad = lane >> 4, l16 = lane & 15;
    const int wr = wave & 1, wc = wave >> 1;      // m-half, n-half
    const int m0 = blockIdx.y * 64, n0 = blockIdx.x * 128;
    const int lr = lane >> 3;
    const int lcs = ((lane & 7) ^ (lr & 7)) * 8;     // swizzled source col
    const int rsw = (l16 & 7) << 3;                  // read-side XOR (elems)

    const bf16* Ag = A + (long)(m0 + wave * 16 + lr) * 1024 + lcs;
    const bf16* Bg = W + (long)(n0 + wave * 32 + lr) * 1024 + lcs;
    const int labase = (wave * 16) * 64 + lane * 8;
    const int lbbase = (wave * 32) * 64 + lane * 8;

    floatx4 acc[2][4] = {};

#pragma unroll
    for (int j = 0; j < 2; ++j)
        async16(Ag + (long)j * 8 * 1024, &As[0][labase + j * 8 * 64]);
#pragma unroll
    for (int j = 0; j < 4; ++j)
        async16(Bg + (long)j * 8 * 1024, &Bs[0][lbbase + j * 8 * 64]);

    for (int ks = 0; ks < 16; ++ks) {
        __syncthreads();
        const int cur = ks & 1;
        if (ks < 15) {
            const int nxt = cur ^ 1, k0 = (ks + 1) * 64;
#pragma unroll
            for (int j = 0; j < 2; ++j)
                async16(Ag + (long)j * 8 * 1024 + k0, &As[nxt][labase + j * 8 * 64]);
#pragma unroll
            for (int j = 0; j < 4; ++j)
                async16(Bg + (long)j * 8 * 1024 + k0, &Bs[nxt][lbbase + j * 8 * 64]);
        }
#pragma unroll
        for (int c = 0; c < 2; ++c) {
            bf16x8 af[2], bfr[4];
#pragma unroll
            for (int mi = 0; mi < 2; ++mi)
                af[mi] = *(const bf16x8*)&As[cur][(wr * 32 + mi * 16 + l16) * 64 + ((c * 32 + quad * 8) ^ rsw)];
#pragma unroll
            for (int ni = 0; ni < 4; ++ni)
                bfr[ni] = *(const bf16x8*)&Bs[cur][(wc * 64 + ni * 16 + l16) * 64 + ((c * 32 + quad * 8) ^ rsw)];
#pragma unroll
            for (int mi = 0; mi < 2; ++mi)
#pragma unroll
                for (int ni = 0; ni < 4; ++ni)
                    acc[mi][ni] = MFMA(af[mi], bfr[ni], acc[mi][ni]);
        }
    }

#pragma unroll
    for (int mi = 0; mi < 2; ++mi)
#pragma unroll
        for (int ni = 0; ni < 4; ++ni) {
            const int n = n0 + wc * 64 + ni * 16 + l16;
            const float bn = bias[n];
#pragma unroll
            for (int r = 0; r < 4; ++r) {
                const int m = m0 + wr * 32 + mi * 16 + quad * 4 + r;
                out[(long)m * 1024 + n] = acc[mi][ni][r] + bn;
            }
        }
}

extern "C" void kernel_launch(void* const* d_in, const int* in_sizes, int n_in,
                              void* d_out, int out_size, void* d_ws, size_t ws_size,
                              hipStream_t stream) {
    const float* query = (const float*)d_in[0];
    // d_in[1] (key), d_in[2] (value) are ignored by the module
    const float* qkv_w = (const float*)d_in[3];
    const float* qkv_b = (const float*)d_in[4];
    const float* out_w = (const float*)d_in[5];
    const float* out_b = (const float*)d_in[6];

    // Workspace layout (bf16 elems):
    //   qb   : 4096*1024   query bf16; REUSED as ctxw after qkv_gemm
    //   wqb  : 3072*1024   qkv_w bf16
    //   owb  : 1024*1024   out_w bf16
    //   Qw/Kw/Vtw : 4096*1024 each
    const long NTOK = (long)BB * SS;          // 4096
    bf16* qb   = (bf16*)d_ws;
    bf16* wqb  = qb  + NTOK * EE;
    bf16* owb  = wqb + (long)3 * EE * EE;
    bf16* Qw   = owb + (long)EE * EE;
    bf16* Kw   = Qw  + NTOK * EE;
    bf16* Vtw  = Kw  + NTOK * EE;
    bf16* ctxw = qb;                          // alias: qb dead after qkv_gemm
    float* out = (float*)d_out;

    cvt3<<<2048, 256, 0, stream>>>(query, qkv_w, out_w, qb, wqb, owb);
    qkv_gemm<<<dim3(NBLK), dim3(512), 0, stream>>>(qb, wqb, qkv_b, Qw, Kw, Vtw);
    attn<<<dim3(16, 32), 512, 65536, stream>>>(Qw, Kw, Vtw, ctxw);
    out_gemm<<<dim3(8, 64), 256, 0, stream>>>(ctxw, owb, out_b, out);
}

// Round 11
// 186.903 us; speedup vs baseline: 1.1432x; 1.1432x over previous
//
#include <hip/hip_runtime.h>
#include <hip/hip_bf16.h>
#include <math.h>

// B=2 S=2048 E=1024 H=16 HD=64
#define BB 2
#define SS 2048
#define EE 1024
#define HH 16
#define HD 64
#define NBLK 512

typedef __bf16 bf16;
typedef __bf16 bf16x8 __attribute__((ext_vector_type(8)));
typedef float floatx4 __attribute__((ext_vector_type(4)));
typedef float floatx16 __attribute__((ext_vector_type(16)));

#define MFMA(a, b, c) __builtin_amdgcn_mfma_f32_16x16x32_bf16(a, b, c, 0, 0, 0)
#define MFMA32(a, b, c) __builtin_amdgcn_mfma_f32_32x32x16_bf16(a, b, c, 0, 0, 0)

// async global->LDS, 16 bytes/lane (global_load_lds_dwordx4)
__device__ inline void async16(const bf16* g, bf16* l) {
    __builtin_amdgcn_global_load_lds(
        (const __attribute__((address_space(1))) void*)g,
        (__attribute__((address_space(3))) void*)l, 16, 0, 0);
}

__device__ inline unsigned cvt_pk_bf16(float a, float b) {
    unsigned r;
    asm("v_cvt_pk_bf16_f32 %0, %1, %2" : "=v"(r) : "v"(a), "v"(b));
    return r;
}

__device__ inline float fast_exp2(float x) {
    float r;
    asm("v_exp_f32 %0, %1" : "=v"(r) : "v"(x));
    return r;
}

// ---------------- Kernel 0: fp32 -> bf16 convert (query, qkv_w, out_w) ------
__global__ __launch_bounds__(256) void cvt3(
    const float* __restrict__ a, const float* __restrict__ b,
    const float* __restrict__ c,
    bf16* __restrict__ oa, bf16* __restrict__ ob, bf16* __restrict__ oc) {
    const long NA = (long)4096 * 1024, NB = (long)3072 * 1024, NC = (long)1024 * 1024;
    const long total = (NA + NB + NC) >> 2;
    long i = (long)blockIdx.x * blockDim.x + threadIdx.x;
    const long stride = (long)gridDim.x * blockDim.x;
    for (; i < total; i += stride) {
        const long e = i << 2;
        const float* src;
        bf16* dst;
        if (e < NA)           { src = a + e;            dst = oa + e; }
        else if (e < NA + NB) { src = b + (e - NA);     dst = ob + (e - NA); }
        else                  { src = c + (e - NA - NB); dst = oc + (e - NA - NB); }
        float4 v = *(const float4*)src;
        union { bf16 h[4]; uint2 u; } t;
        t.h[0] = (bf16)v.x; t.h[1] = (bf16)v.y; t.h[2] = (bf16)v.z; t.h[3] = (bf16)v.w;
        *(uint2*)dst = t.u;
    }
}

// ---------------- Kernel 1: QKV projection, 8-wave 128x128x64 dbuf ---------
// Round-8 verified version, reverted verbatim (round-10's K-split combine
// cost more than its ds_read saving: 198.9 -> 213.7 regression).
__global__ __launch_bounds__(512, 4) void qkv_gemm(
    const bf16* __restrict__ A, const bf16* __restrict__ W,
    const float* __restrict__ bias,
    bf16* __restrict__ Qw, bf16* __restrict__ Kw, bf16* __restrict__ Vtw) {
    __shared__ __align__(16) bf16 smem[32768];   // 64 KB: As0|As1|Bs0|Bs1
    const int bid  = blockIdx.x;
    const int tid  = threadIdx.x;
    const int wave = tid >> 6, lane = tid & 63;
    const int quad = lane >> 4, l16 = lane & 15;
    const int wr = wave >> 2, wc = wave & 3;         // wave owns 64m x 32n
    const int lr = lane >> 3;
    const int lcs = ((lane & 7) ^ (lr & 7)) * 8;     // swizzled source col
    const int rsw = (l16 & 7) << 3;                  // read-side XOR (elems)
    bf16* As0 = smem;         bf16* As1 = smem + 8192;
    bf16* Bs0 = smem + 16384; bf16* Bs1 = smem + 24576;
    const bool stA = wave < 4;                       // waves 0-3 stage A, 4-7 B
    const int sw = wave & 3;
    bf16* L0g = (stA ? As0 : Bs0) + sw * 2048 + lane * 8;
    bf16* L1g = (stA ? As1 : Bs1) + sw * 2048 + lane * 8;

    for (int tile = bid; tile < 768; tile += NBLK) {
        const int m0 = (tile / 24) * 128, n0 = (tile % 24) * 128;
        const bf16* G = stA
            ? (A + (long)(m0 + sw * 32 + lr) * 1024 + lcs)
            : (W + (long)(n0 + sw * 32 + lr) * 1024 + lcs);
        floatx4 acc[4][2] = {};
#pragma unroll
        for (int j = 0; j < 4; ++j)
            async16(G + (long)j * 8 * 1024, L0g + j * 512);
        for (int ks = 0; ks < 16; ++ks) {
            __syncthreads();   // drains vmcnt: buf cur ready; readers of nxt done
            if (ks < 15) {
                bf16* Ln = (ks & 1) ? L0g : L1g;
                const int k0 = (ks + 1) * 64;
#pragma unroll
                for (int j = 0; j < 4; ++j)
                    async16(G + (long)j * 8 * 1024 + k0, Ln + j * 512);
            }
            const bf16* Ac = (ks & 1) ? As1 : As0;
            const bf16* Bc = (ks & 1) ? Bs1 : Bs0;
#pragma unroll
            for (int c = 0; c < 2; ++c) {
                bf16x8 af[4], bfr[2];
#pragma unroll
                for (int mi = 0; mi < 4; ++mi)
                    af[mi] = *(const bf16x8*)&Ac[(wr * 64 + mi * 16 + l16) * 64 + ((c * 32 + quad * 8) ^ rsw)];
#pragma unroll
                for (int ni = 0; ni < 2; ++ni)
                    bfr[ni] = *(const bf16x8*)&Bc[(wc * 32 + ni * 16 + l16) * 64 + ((c * 32 + quad * 8) ^ rsw)];
#pragma unroll
                for (int mi = 0; mi < 4; ++mi)
#pragma unroll
                    for (int ni = 0; ni < 2; ++ni)
                        acc[mi][ni] = MFMA(af[mi], bfr[ni], acc[mi][ni]);
            }
        }
#pragma unroll
        for (int mi = 0; mi < 4; ++mi)
#pragma unroll
            for (int ni = 0; ni < 2; ++ni) {
                const int n = n0 + wc * 32 + ni * 16 + l16;
                const float bn = bias[n];
                const int sel = n >> 10;        // 0:Q 1:K 2:V (uniform/block)
                const int e = n & 1023, h = e >> 6, d = e & 63;
                if (sel == 2) {
                    const int m_base = m0 + wr * 64 + mi * 16 + quad * 4;
                    const int b = m_base >> 11, s0 = m_base & 2047;
                    union { bf16 h4[4]; uint2 u; } t;
#pragma unroll
                    for (int r = 0; r < 4; ++r)
                        t.h4[r] = (bf16)(acc[mi][ni][r] + bn);
                    *(uint2*)&Vtw[((long)(b * HH + h) * HD + d) * SS + s0] = t.u;
                } else {
#pragma unroll
                    for (int r = 0; r < 4; ++r) {
                        const int m = m0 + wr * 64 + mi * 16 + quad * 4 + r;
                        const int b = m >> 11, s = m & 2047;
                        const float v = acc[mi][ni][r] + bn;
                        if (sel == 0)   // 1/sqrt(HD) * log2(e) for exp2
                            Qw[((long)(b * HH + h) * SS + s) * HD + d] = (bf16)(v * 0.18033688f);
                        else
                            Kw[((long)(b * HH + h) * SS + s) * HD + d] = (bf16)v;
                    }
                }
            }
        __syncthreads();   // all reads of this tile's LDS done before restage
    }
}

// ---------------- Kernel 2: attention, 8 waves, in-block 2-way KV split ----
// (round-5/8 passing version, unchanged)
__global__ __launch_bounds__(512) void attn(
    const bf16* __restrict__ Qw, const bf16* __restrict__ Kw,
    const bf16* __restrict__ Vtw, bf16* __restrict__ ctxw) {
    extern __shared__ __align__(16) bf16 smem[];

    const int tid = threadIdx.x;
    const int wave = tid >> 6, lane = tid & 63;
    const int grp = wave >> 2, w4 = wave & 3;
    const int l5 = lane & 31, hi = lane >> 5;

    // T1 remap: xcd = d&7 serves bh in [xcd*4, xcd*4+4) for all 16 qb.
    const int d_  = blockIdx.y * gridDim.x + blockIdx.x;
    const int j_  = d_ >> 3;
    const int bh  = (d_ & 7) * 4 + (j_ >> 4);
    const int qb  = j_ & 15;

    const bf16* Qh = Qw  + (long)bh * SS * HD;
    const bf16* Kh = Kw  + (long)bh * SS * HD;
    const bf16* Vh = Vtw + (long)bh * HD * SS;

    const int qbase = qb * 128 + w4 * 32;
    bf16x8 qf[4];
#pragma unroll
    for (int d0 = 0; d0 < 4; ++d0)
        qf[d0] = *(const bf16x8*)&Qh[(long)(qbase + l5) * HD + d0 * 16 + hi * 8];

    floatx16 ctx0 = {}, ctx1 = {};       // partial ctx over this group's KV half
    float lsum = 0.f;                    // partial row-sum for q = l5

    const int wrow = w4 * 8 + (lane >> 3);
    const int sch  = ((lane & 7) ^ ((lane >> 3) & 7)) * 8;
    const int kvo  = grp * 1024;          // this group's KV half
    const bf16* Kg0 = Kh + (long)(kvo + wrow) * HD + sch;
    const bf16* Kg1 = Kh + (long)(kvo + 32 + wrow) * HD + sch;
    const bf16* Vg0 = Vh + (long)wrow * SS + kvo + sch;
    const bf16* Vg1 = Vh + (long)(32 + wrow) * SS + kvo + sch;
    const int ldst = w4 * 512 + lane * 8;
    const int rswz = (l5 & 7) << 3;

    bf16* Kt0 = smem + (grp * 2 + 0) * 4096;
    bf16* Kt1 = smem + (grp * 2 + 1) * 4096;
    bf16* Vt0 = smem + 16384 + (grp * 2 + 0) * 4096;
    bf16* Vt1 = smem + 16384 + (grp * 2 + 1) * 4096;

    async16(Kg0, Kt0 + ldst);
    async16(Kg1, Kt0 + ldst + 2048);
    async16(Vg0, Vt0 + ldst);
    async16(Vg1, Vt0 + ldst + 2048);

    for (int kt = 0; kt < 16; ++kt) {
        __syncthreads();
        if (kt < 15) {
            bf16* Kn = (kt & 1) ? Kt0 : Kt1;
            bf16* Vn = (kt & 1) ? Vt0 : Vt1;
            const long ko = (long)(kt + 1) * 64;
            async16(Kg0 + ko * HD, Kn + ldst);
            async16(Kg1 + ko * HD, Kn + ldst + 2048);
            async16(Vg0 + ko,      Vn + ldst);
            async16(Vg1 + ko,      Vn + ldst + 2048);
        }
        const bf16* Kc = (kt & 1) ? Kt1 : Kt0;
        const bf16* Vc = (kt & 1) ? Vt1 : Vt0;

        floatx16 sf[2];
#pragma unroll
        for (int kb = 0; kb < 2; ++kb) {
            floatx16 s = {};
            __builtin_amdgcn_s_setprio(1);
#pragma unroll
            for (int d0 = 0; d0 < 4; ++d0) {
                const bf16x8 af = *(const bf16x8*)
                    &Kc[(kb * 32 + l5) * 64 + ((d0 * 16 + hi * 8) ^ rswz)];
                s = MFMA32(af, qf[d0], s);
            }
            __builtin_amdgcn_s_setprio(0);
            sf[kb] = s;
        }

#pragma unroll
        for (int kb = 0; kb < 2; ++kb) {
#pragma unroll
            for (int r = 0; r < 16; ++r) {
                const float p = fast_exp2(sf[kb][r]);
                sf[kb][r] = p;
                lsum += p;
            }
            unsigned w[8];
#pragma unroll
            for (int i = 0; i < 8; ++i)
                w[i] = cvt_pk_bf16(sf[kb][2 * i], sf[kb][2 * i + 1]);
            asm("v_permlane32_swap_b32 %0, %1" : "+v"(w[0]), "+v"(w[2]));
            asm("v_permlane32_swap_b32 %0, %1" : "+v"(w[1]), "+v"(w[3]));
            asm("v_permlane32_swap_b32 %0, %1" : "+v"(w[4]), "+v"(w[6]));
            asm("v_permlane32_swap_b32 %0, %1" : "+v"(w[5]), "+v"(w[7]));
            union { unsigned u[4]; bf16x8 v; } pa0 = {{w[0], w[1], w[2], w[3]}},
                                               pa1 = {{w[4], w[5], w[6], w[7]}};
#pragma unroll
            for (int kc = 0; kc < 2; ++kc) {
                const bf16x8 pa = kc ? pa1.v : pa0.v;
                const int kcol = kb * 32 + kc * 16 + hi * 8;
                const bf16x8 vf0 = *(const bf16x8*)&Vc[l5 * 64 + (kcol ^ rswz)];
                const bf16x8 vf1 = *(const bf16x8*)&Vc[(32 + l5) * 64 + (kcol ^ rswz)];
                __builtin_amdgcn_s_setprio(1);
                ctx0 = MFMA32(pa, vf0, ctx0);
                ctx1 = MFMA32(pa, vf1, ctx1);
                __builtin_amdgcn_s_setprio(0);
            }
        }
    }

    // combine the two KV halves (exact: no-rescale partials just add)
    __syncthreads();
    float* cb = (float*)smem;              // [4][32][64] = 32 KB
    float* lb = (float*)(smem + 16384);    // [4][64]
    if (grp == 1) {
#pragma unroll
        for (int r = 0; r < 16; ++r) {
            cb[(w4 * 32 + r) * 64 + lane]      = ctx0[r];
            cb[(w4 * 32 + 16 + r) * 64 + lane] = ctx1[r];
        }
        lb[w4 * 64 + lane] = lsum;
    }
    __syncthreads();
    if (grp == 0) {
        lsum += lb[w4 * 64 + lane];
#pragma unroll
        for (int r = 0; r < 16; ++r) {
            ctx0[r] += cb[(w4 * 32 + r) * 64 + lane];
            ctx1[r] += cb[(w4 * 32 + 16 + r) * 64 + lane];
        }
        const float rs  = lsum + __shfl_xor(lsum, 32, 64);
        const float inv = 1.0f / rs;

        const int b = bh >> 4, h = bh & 15;
#pragma unroll
        for (int r = 0; r < 16; ++r) {
            const int qrow = (r & 3) + 8 * (r >> 2) + 4 * hi;
            const float iq = __shfl(inv, qrow, 64);
            const long base = ((long)b * SS + qbase + qrow) * EE + h * HD;
            ctxw[base + l5]      = (bf16)(ctx0[r] * iq);
            ctxw[base + 32 + l5] = (bf16)(ctx1[r] * iq);
        }
    }
}

// ---------------- Kernel 3: output projection, 8-wave 64x128 dbuf ----------
// Round-11: occupancy lever applied (was 256 thr -> 8 waves/CU = 2/SIMD,
// 16us vs ~4.1us memory floor / ~3.4us MFMA floor => latency-bound).
// Now 512 thr, wave owns 32x32 (wr=wave>>2, wc=wave&3, acc[2][2]); waves
// 0-1 stage A (64 rows), waves 4-7 stage B (128 rows); LDS 48 KB ->
// 2 blocks/CU x 8 waves = 16 waves/CU. Same dbuf rhythm, same rule-21
// source-side swizzle + read XOR, same epilogue algebra as the r5-verified
// version. (Also standalone-validates the mega phase-3 structure.)
__global__ __launch_bounds__(512, 4) void out_gemm(
    const bf16* __restrict__ A, const bf16* __restrict__ W,
    const float* __restrict__ bias, float* __restrict__ out) {
    __shared__ __align__(16) bf16 smem[24576];   // 48 KB: As0|As1|Bs0|Bs1
    const int tid  = threadIdx.x;
    const int wave = tid >> 6, lane = tid & 63;
    const int quad = lane >> 4, l16 = lane & 15;
    const int wr = wave >> 2, wc = wave & 3;      // wave owns 32m x 32n
    const int m0 = blockIdx.y * 64, n0 = blockIdx.x * 128;
    const int lr = lane >> 3;
    const int lcs = ((lane & 7) ^ (lr & 7)) * 8;     // swizzled source col
    const int rsw = (l16 & 7) << 3;                  // read-side XOR (elems)
    bf16* As0 = smem;         bf16* As1 = smem + 4096;    // 64x64 each
    bf16* Bs0 = smem + 8192;  bf16* Bs1 = smem + 16384;   // 128x64 each

    const bool stA = wave < 2;                    // waves 0-1: A; 4-7: B
    const bool doStage = (wave < 2) || (wave >= 4);
    const int swA = wave & 1, swB = wave & 3;
    const bf16* G = stA
        ? (A + (long)(m0 + swA * 32 + lr) * 1024 + lcs)
        : (W + (long)(n0 + swB * 32 + lr) * 1024 + lcs);
    bf16* L0 = stA ? As0 + swA * 2048 + lane * 8 : Bs0 + swB * 2048 + lane * 8;
    bf16* L1 = stA ? As1 + swA * 2048 + lane * 8 : Bs1 + swB * 2048 + lane * 8;

    floatx4 acc[2][2] = {};

    if (doStage)
#pragma unroll
        for (int j = 0; j < 4; ++j)
            async16(G + (long)j * 8 * 1024, L0 + j * 512);

    for (int ks = 0; ks < 16; ++ks) {
        __syncthreads();   // drains vmcnt: buf cur ready; readers of nxt done
        if (ks < 15 && doStage) {
            bf16* Ln = (ks & 1) ? L0 : L1;
            const int k0 = (ks + 1) * 64;
#pragma unroll
            for (int j = 0; j < 4; ++j)
                async16(G + (long)j * 8 * 1024 + k0, Ln + j * 512);
        }
        const bf16* Ac = (ks & 1) ? As1 : As0;
        const bf16* Bc = (ks & 1) ? Bs1 : Bs0;
#pragma unroll
        for (int c = 0; c < 2; ++c) {
            bf16x8 af[2], bfr[2];
#pragma unroll
            for (int mi = 0; mi < 2; ++mi)
                af[mi] = *(const bf16x8*)&Ac[(wr * 32 + mi * 16 + l16) * 64 + ((c * 32 + quad * 8) ^ rsw)];
#pragma unroll
            for (int ni = 0; ni < 2; ++ni)
                bfr[ni] = *(const bf16x8*)&Bc[(wc * 32 + ni * 16 + l16) * 64 + ((c * 32 + quad * 8) ^ rsw)];
#pragma unroll
            for (int mi = 0; mi < 2; ++mi)
#pragma unroll
                for (int ni = 0; ni < 2; ++ni)
                    acc[mi][ni] = MFMA(af[mi], bfr[ni], acc[mi][ni]);
        }
    }

#pragma unroll
    for (int mi = 0; mi < 2; ++mi)
#pragma unroll
        for (int ni = 0; ni < 2; ++ni) {
            const int n = n0 + wc * 32 + ni * 16 + l16;
            const float bn = bias[n];
#pragma unroll
            for (int r = 0; r < 4; ++r) {
                const int m = m0 + wr * 32 + mi * 16 + quad * 4 + r;
                out[(long)m * 1024 + n] = acc[mi][ni][r] + bn;
            }
        }
}

extern "C" void kernel_launch(void* const* d_in, const int* in_sizes, int n_in,
                              void* d_out, int out_size, void* d_ws, size_t ws_size,
                              hipStream_t stream) {
    const float* query = (const float*)d_in[0];
    // d_in[1] (key), d_in[2] (value) are ignored by the module
    const float* qkv_w = (const float*)d_in[3];
    const float* qkv_b = (const float*)d_in[4];
    const float* out_w = (const float*)d_in[5];
    const float* out_b = (const float*)d_in[6];

    // Workspace layout (bf16 elems):
    //   qb   : 4096*1024   query bf16; REUSED as ctxw after qkv_gemm
    //   wqb  : 3072*1024   qkv_w bf16
    //   owb  : 1024*1024   out_w bf16
    //   Qw/Kw/Vtw : 4096*1024 each
    const long NTOK = (long)BB * SS;          // 4096
    bf16* qb   = (bf16*)d_ws;
    bf16* wqb  = qb  + NTOK * EE;
    bf16* owb  = wqb + (long)3 * EE * EE;
    bf16* Qw   = owb + (long)EE * EE;
    bf16* Kw   = Qw  + NTOK * EE;
    bf16* Vtw  = Kw  + NTOK * EE;
    bf16* ctxw = qb;                          // alias: qb dead after qkv_gemm
    float* out = (float*)d_out;

    cvt3<<<2048, 256, 0, stream>>>(query, qkv_w, out_w, qb, wqb, owb);
    qkv_gemm<<<dim3(NBLK), dim3(512), 0, stream>>>(qb, wqb, qkv_b, Qw, Kw, Vtw);
    attn<<<dim3(16, 32), 512, 65536, stream>>>(Qw, Kw, Vtw, ctxw);
    out_gemm<<<dim3(8, 64), 512, 0, stream>>>(ctxw, owb, out_b, out);
}